// Round 8
// baseline (167.155 us; speedup 1.0000x reference)
//
#include <hip/hip_runtime.h>
#include <hip/hip_bf16.h>
#include <stdint.h>

#define B_DIM 8
#define C_DIM 128
#define N_SP 2304
#define NT 18                      // 2304 / 128
#define NTRI 171                   // NT*(NT+1)/2
#define NTILES (2 * B_DIM * NTRI)  // 2736 tiles
#define GRID_G (NTILES / 2)        // 1368 blocks, 2 tiles each; 1368 % 8 == 0

typedef __attribute__((ext_vector_type(8))) short short8;
typedef __attribute__((ext_vector_type(4))) float f32x4;

__device__ __forceinline__ uint32_t f2bf(float f) {
    uint32_t u = __float_as_uint(f);
    return (u + 0x7fffu + ((u >> 16) & 1u)) >> 16;    // RNE
}

// ---- prep: fp32 [C][N] -> bf16 [N][C] rows (16B chunks swizzled by n&7) + fp32 rinv
__global__ __launch_bounds__(256) void prep_kernel(
    const float* __restrict__ x0, const float* __restrict__ x1,
    const float* __restrict__ x2, const float* __restrict__ x3,
    ushort* __restrict__ xt, float* __restrict__ rinv, float* __restrict__ accum)
{
    __shared__ ushort stage[64 * 128];    // 16 KB

    int bid = blockIdx.x;                 // 4 * 8 * 36
    if (bid == 0 && threadIdx.x < 64) accum[threadIdx.x] = 0.f;   // replaces memset
    int t  = bid / 288;
    int b  = (bid / 36) % 8;
    int nb = bid % 36;
    int tid = threadIdx.x;
    int q   = tid & 3;                    // c-quarter
    int nl  = tid >> 2;                   // local n 0..63
    int n   = nb * 64 + nl;
    const float* x  = t == 0 ? x0 : t == 1 ? x1 : t == 2 ? x2 : x3;
    const float* xb = x + (size_t)b * (C_DIM * N_SP) + n;
    int sw = nl & 7;

    float s = 0.f;
#pragma unroll
    for (int jj = 0; jj < 4; ++jj) {
        uint32_t w[4];
#pragma unroll
        for (int m = 0; m < 4; ++m) {
            int c = q * 32 + jj * 8 + m * 2;
            float v0 = xb[(size_t)c * N_SP];
            float v1 = xb[(size_t)(c + 1) * N_SP];
            s = fmaf(v0, v0, s);
            s = fmaf(v1, v1, s);
            w[m] = f2bf(v0) | (f2bf(v1) << 16);
        }
        int J = q * 4 + jj;
        uint4 u; u.x = w[0]; u.y = w[1]; u.z = w[2]; u.w = w[3];
        *(uint4*)&stage[nl * 128 + ((J ^ sw) * 8)] = u;
    }
    s += __shfl_xor(s, 1, 64);
    s += __shfl_xor(s, 2, 64);
    if (q == 0) rinv[(size_t)(t * 8 + b) * N_SP + n] = 1.f / (sqrtf(s) + 1e-8f);

    __syncthreads();
    ushort* dst = xt + ((size_t)(t * 8 + b) * N_SP + (size_t)nb * 64) * 128;
#pragma unroll
    for (int it = 0; it < 4; ++it)
        *(uint4*)(dst + it * 2048 + tid * 8) = *(const uint4*)(stage + it * 2048 + tid * 8);
}

// ---- gram: 2 tiles per block, 8-round counted-vmcnt pipeline, bf16 MFMA
struct TileInfo {
    const ushort* xo; const ushort* xg;
    const float*  ro; const float*  rg;
    int tn, tm; float w2; int pair;
};

__device__ __forceinline__ TileInfo decode_tile(int g, const ushort* xt, const float* rinv) {
    int pair = g / (B_DIM * NTRI);
    int rem  = g - pair * (B_DIM * NTRI);
    int b    = rem / NTRI;
    int t    = rem - b * NTRI;
    int tn = 0, cnt = NT;
    while (t >= cnt) { t -= cnt; --cnt; ++tn; }
    TileInfo ti;
    ti.tn = tn; ti.tm = tn + t;
    ti.xo = xt + (size_t)(pair * 8 + b) * N_SP * 128;
    ti.xg = xt + (size_t)((pair + 2) * 8 + b) * N_SP * 128;
    ti.ro = rinv + (size_t)(pair * 8 + b) * N_SP;
    ti.rg = rinv + (size_t)((pair + 2) * 8 + b) * N_SP;
    ti.w2 = (tn == ti.tm) ? 1.f : 2.f;
    ti.pair = pair;
    return ti;
}

// each wave issues exactly 8 global_load_lds (16B) per STAGE
#define STAGE(sbase, TN, TM, h, PA, PB)                                             \
    {                                                                               \
        const ushort* sb = (wid & 2) ? (sbase) + (size_t)(TM) * 16384               \
                                     : (sbase) + (size_t)(TN) * 16384;              \
        ushort* pp = (wid & 2) ? (PB) : (PA);                                       \
        int i0 = (wid & 1) * 8;                                                     \
        _Pragma("unroll")                                                           \
        for (int i = 0; i < 8; ++i) {                                               \
            int ii = i0 + i;                                                        \
            int col = ii * 8 + (lane >> 3);                                         \
            const ushort* src = sb + (size_t)col * 128 + (h) * 64 + (lane & 7) * 8; \
            __builtin_amdgcn_global_load_lds(                                       \
                (const __attribute__((address_space(1))) uint32_t*)src,             \
                (__attribute__((address_space(3))) uint32_t*)(pp + ii * 512),       \
                16, 0, 0);                                                          \
        }                                                                           \
    }

#define COMPUTE(ACC, PA, PB)                                                        \
    _Pragma("unroll")                                                               \
    for (int s = 0; s < 2; ++s) {                                                   \
        short8 av[4], bv[4];                                                        \
        int g = lane >> 4;                                                          \
        _Pragma("unroll")                                                           \
        for (int i = 0; i < 4; ++i) {                                               \
            int ca = wrow * 64 + i * 16 + (lane & 15);                              \
            av[i] = *(const short8*)&(PA)[ca * 64 + ((s * 4 + g) ^ (ca & 7)) * 8];  \
            int cb = wcol * 64 + i * 16 + (lane & 15);                              \
            bv[i] = *(const short8*)&(PB)[cb * 64 + ((s * 4 + g) ^ (cb & 7)) * 8];  \
        }                                                                           \
        _Pragma("unroll")                                                           \
        for (int i = 0; i < 4; ++i)                                                 \
            _Pragma("unroll")                                                       \
            for (int j = 0; j < 4; ++j)                                             \
                ACC[i][j] = __builtin_amdgcn_mfma_f32_16x16x32_bf16(                \
                    av[i], bv[j], ACC[i][j], 0, 0, 0);                              \
    }

#define ZERO_ACC()                                                                  \
    _Pragma("unroll")                                                               \
    for (int i = 0; i < 4; ++i)                                                     \
        _Pragma("unroll")                                                           \
        for (int j = 0; j < 4; ++j) {                                               \
            acc_o[i][j] = (f32x4){0.f, 0.f, 0.f, 0.f};                              \
            acc_t[i][j] = (f32x4){0.f, 0.f, 0.f, 0.f};                              \
        }

// per-wave epilogue: OUT (lane 0) = wave's weighted sum of |so - st|
#define EPILOGUE_REG(Q, W2, OUT)                                                    \
    {                                                                               \
        int fr = lane & 15, fq = lane >> 4;                                         \
        float co[4], cg[4];                                                         \
        _Pragma("unroll")                                                           \
        for (int j = 0; j < 4; ++j) {                                               \
            co[j] = rn[Q][1][wcol * 64 + j * 16 + fr];                              \
            cg[j] = rn[Q][3][wcol * 64 + j * 16 + fr];                              \
        }                                                                           \
        float lsum = 0.f;                                                           \
        _Pragma("unroll")                                                           \
        for (int i = 0; i < 4; ++i) {                                               \
            _Pragma("unroll")                                                       \
            for (int r = 0; r < 4; ++r) {                                           \
                int rowl = wrow * 64 + i * 16 + fq * 4 + r;                         \
                float ror = rn[Q][0][rowl], rgr = rn[Q][2][rowl];                   \
                _Pragma("unroll")                                                   \
                for (int j = 0; j < 4; ++j) {                                       \
                    float so = acc_o[i][j][r] * ror * co[j];                        \
                    float st = acc_t[i][j][r] * rgr * cg[j];                        \
                    lsum += fabsf(so - st);                                         \
                }                                                                   \
            }                                                                       \
        }                                                                           \
        lsum *= (W2);                                                               \
        _Pragma("unroll")                                                           \
        for (int off = 32; off > 0; off >>= 1) lsum += __shfl_down(lsum, off, 64);  \
        OUT = lsum;                                                                 \
    }

// round skeleton: safe-overwrite barrier, issue next stage, counted wait, data barrier
#define RBAR()    __builtin_amdgcn_s_barrier()
#define WAIT8()   asm volatile("s_waitcnt vmcnt(8)" ::: "memory")
#define WAIT0()   asm volatile("s_waitcnt vmcnt(0)" ::: "memory")

__global__ __launch_bounds__(256, 2) void gram_kernel(
    const ushort* __restrict__ xt, const float* __restrict__ rinv,
    float* __restrict__ accum)
{
    __shared__ ushort pA[2][128 * 64];
    __shared__ ushort pB[2][128 * 64];
    __shared__ float rn[2][4][128];

    int bid0 = blockIdx.x;
    int bid  = (bid0 & 7) * (GRID_G / 8) + (bid0 >> 3);   // XCD chunking (bijective)

    TileInfo t0 = decode_tile(2 * bid,     xt, rinv);
    TileInfo t1 = decode_tile(2 * bid + 1, xt, rinv);

    int tid  = threadIdx.x;
    int wid  = tid >> 6;
    int lane = tid & 63;
    int wrow = wid >> 1, wcol = wid & 1;

    f32x4 acc_o[4][4], acc_t[4][4];
    ZERO_ACC();
    float sum0, sum1;

    // prologue: S0 + norms, full drain
    STAGE(t0.xo, t0.tn, t0.tm, 0, pA[0], pB[0]);
    if (tid < 128) {
        rn[0][0][tid] = t0.ro[t0.tn * 128 + tid];
        rn[0][1][tid] = t0.ro[t0.tm * 128 + tid];
        rn[1][0][tid] = t1.ro[t1.tn * 128 + tid];
        rn[1][1][tid] = t1.ro[t1.tm * 128 + tid];
    } else {
        int u = tid - 128;
        rn[0][2][u] = t0.rg[t0.tn * 128 + u];
        rn[0][3][u] = t0.rg[t0.tm * 128 + u];
        rn[1][2][u] = t1.rg[t1.tn * 128 + u];
        rn[1][3][u] = t1.rg[t1.tm * 128 + u];
    }
    __syncthreads();
    STAGE(t0.xo, t0.tn, t0.tm, 1, pA[1], pB[1]);          // S1, 8 in flight
    COMPUTE(acc_o, pA[0], pB[0]);                          // r0

    RBAR();                                                // all done reading pA/pB[0]
    STAGE(t0.xg, t0.tn, t0.tm, 0, pA[0], pB[0]);          // S2, 16 in flight
    WAIT8(); RBAR();                                       // S1 landed everywhere
    COMPUTE(acc_o, pA[1], pB[1]);                          // r1

    RBAR();
    STAGE(t0.xg, t0.tn, t0.tm, 1, pA[1], pB[1]);          // S3
    WAIT8(); RBAR();                                       // S2 ready
    COMPUTE(acc_t, pA[0], pB[0]);                          // r2

    RBAR();
    STAGE(t1.xo, t1.tn, t1.tm, 0, pA[0], pB[0]);          // S4
    WAIT8(); RBAR();                                       // S3 ready
    COMPUTE(acc_t, pA[1], pB[1]);                          // r3
    EPILOGUE_REG(0, t0.w2, sum0);                          // tile0 done (overlaps S4)
    ZERO_ACC();

    RBAR();
    STAGE(t1.xo, t1.tn, t1.tm, 1, pA[1], pB[1]);          // S5
    WAIT8(); RBAR();                                       // S4 ready
    COMPUTE(acc_o, pA[0], pB[0]);                          // r4

    RBAR();
    STAGE(t1.xg, t1.tn, t1.tm, 0, pA[0], pB[0]);          // S6
    WAIT8(); RBAR();                                       // S5 ready
    COMPUTE(acc_o, pA[1], pB[1]);                          // r5

    RBAR();
    STAGE(t1.xg, t1.tn, t1.tm, 1, pA[1], pB[1]);          // S7
    WAIT8(); RBAR();                                       // S6 ready
    COMPUTE(acc_t, pA[0], pB[0]);                          // r6

    RBAR();
    WAIT0(); RBAR();                                       // S7 ready
    COMPUTE(acc_t, pA[1], pB[1]);                          // r7
    EPILOGUE_REG(1, t1.w2, sum1);

    if (lane == 0) {
        atomicAdd(&accum[t0.pair * 32 + (bid0 & 31)], sum0);
        atomicAdd(&accum[t1.pair * 32 + (bid0 & 31)], sum1);
    }
}

__global__ void finalize_kernel(const float* __restrict__ a, float* __restrict__ out) {
    float s = a[threadIdx.x];
#pragma unroll
    for (int off = 32; off > 0; off >>= 1) s += __shfl_down(s, off, 64);
    if (threadIdx.x == 0) out[0] = s * (1.0f / 42467328.0f);
}

extern "C" void kernel_launch(void* const* d_in, const int* in_sizes, int n_in,
                              void* d_out, int out_size, void* d_ws, size_t ws_size,
                              hipStream_t stream) {
    const float* o0 = (const float*)d_in[0];
    const float* o1 = (const float*)d_in[1];
    const float* t0 = (const float*)d_in[2];
    const float* t1 = (const float*)d_in[3];

    ushort* xtw  = (ushort*)d_ws;                                   // 18,874,368 B
    float*  rinv = (float*)((char*)d_ws + (size_t)4 * 8 * N_SP * 256);
    float*  accum = rinv + 4 * 8 * N_SP;                            // 64 floats

    prep_kernel<<<1152, 256, 0, stream>>>(o0, o1, t0, t1, xtw, rinv, accum);
    gram_kernel<<<GRID_G, 256, 0, stream>>>(xtw, rinv, accum);
    finalize_kernel<<<1, 64, 0, stream>>>(accum, (float*)d_out);
}